// Round 1
// baseline (187.561 us; speedup 1.0000x reference)
//
#include <hip/hip_runtime.h>
#include <cfloat>

// Problem constants: inputs (64,256,512) fp32, emb (1024,512) fp32.
#define NROWS  16384          // 64*256
#define DIM    512
#define KC     1024
#define QELEMS (NROWS * DIM)  // 8388608
// d_out layout (fp32): [0]=loss, [1 .. QELEMS]=quantized, [1+QELEMS .. +NROWS]=indices (as float)

#define NSPLIT 8              // one per 128-code column block
#define CHUNKS 130            // padded kq-plane stride in 16B chunks (128 rows + 2 pad)
                              // 130*16B = 520 words -> kq-stride == 8 banks (mod 32):
                              // staging writes from 8 consecutive lanes hit 32 distinct banks
                              // (old 132 gave stride==16 -> kq 0/2 and 1/3 collided)

typedef float  floatx4 __attribute__((ext_vector_type(4)));
typedef _Float16 half8 __attribute__((ext_vector_type(8)));
typedef _Float16 half4 __attribute__((ext_vector_type(4)));

// ---------------- kernel 1: fused prep (A and E) ----------------
// blocks [0,4096): A rows; [4096,4352): E rows. rowsq tree + split math VERBATIM
// from the passing rounds (part of the verified rounding structure).
__global__ __launch_bounds__(256) void prep_kernel(const float* __restrict__ A,
                                                   const float* __restrict__ E,
                                                   float* __restrict__ xsq,
                                                   float* __restrict__ esq,
                                                   _Float16* __restrict__ ah,
                                                   _Float16* __restrict__ al,
                                                   _Float16* __restrict__ eh,
                                                   _Float16* __restrict__ el,
                                                   unsigned long long* __restrict__ packed,
                                                   float* __restrict__ out) {
    if (blockIdx.x == 0 && threadIdx.x == 0) out[0] = 0.f;
    const int wave = threadIdx.x >> 6, lane = threadIdx.x & 63;
    const bool isA = blockIdx.x < (NROWS / 4);
    const int row = (isA ? blockIdx.x : blockIdx.x - NROWS / 4) * 4 + wave;
    const float* M = isA ? A : E;
    const float scale = isA ? 2048.0f : 65536.0f;

    const float4* Mr = (const float4*)(M + (size_t)row * DIM);
    float4 va = Mr[lane];
    float4 vb = Mr[lane + 64];
    float s = 0.f;
    s += va.x*va.x + va.y*va.y + va.z*va.z + va.w*va.w;   // same tree as rowsq i=0
    s += vb.x*vb.x + vb.y*vb.y + vb.z*vb.z + vb.w*vb.w;   // i=1
    #pragma unroll
    for (int off = 32; off; off >>= 1) s += __shfl_down(s, off, 64);
    if (lane == 0) {
        if (isA) { xsq[row] = s; packed[row] = ~0ULL; }
        else     { esq[row] = s; }
    }

    float xa[4] = {va.x, va.y, va.z, va.w}, xb[4] = {vb.x, vb.y, vb.z, vb.w};
    half4 ha, la, hb, lb;
    #pragma unroll
    for (int e = 0; e < 4; ++e) {
        float t = xa[e] * scale;
        _Float16 h = (_Float16)t;
        ha[e] = h; la[e] = (_Float16)(t - (float)h);
        t = xb[e] * scale;
        h = (_Float16)t;
        hb[e] = h; lb[e] = (_Float16)(t - (float)h);
    }
    _Float16* hr = (isA ? ah : eh) + (size_t)row * DIM;
    _Float16* lr = (isA ? al : el) + (size_t)row * DIM;
    ((half4*)hr)[lane]      = ha;
    ((half4*)lr)[lane]      = la;
    ((half4*)hr)[lane + 64] = hb;
    ((half4*)lr)[lane + 64] = lb;
}

// ---------------- kernel 2: MFMA distance GEMM + fused argmin ----------------
// Counter-driven restructure vs previous round (77.6us, MfmaUtil 28%, Occ 19.6%,
// LDS 68KB -> 2 blocks/CU, SQ_LDS_BANK_CONFLICT == 8/ds_read_b128 exactly):
//   * E-fragments now read DIRECTLY from global per-lane (no LDS staging).
//     E hi+lo is 2MB total, shared by all 1024 blocks -> guaranteed L2-resident.
//     Each fb load: 16B/lane, qd-groups (4 lanes) share one 64B line.
//     These loads have no barrier dependence -> latency hides under the barrier.
//   * LDS halves to ~35KB (A only) -> 3 blocks/CU (reg-limited), 12 waves/CU.
//   * ds_read count halves, ds_write count halves -> conflict cycles ~halve.
//   * CHUNKS 132->130 so staging-write kq-planes spread over all 32 banks.
// A staging keeps the round-6-proven VGPR-staged double-LDS-buffer, single
// barrier per kt. Score keeps the PASSING rounding structure:
// s = fl( fl(sqx+sqe) - acc*2^-26 ). MFMA order per acc element unchanged
// (hi*bh, hi*bl, lo*bh) -> bit-identical accumulation.
__global__ __launch_bounds__(256, 3) void mfma_argmin_kernel(const _Float16* __restrict__ ah,
                                                             const _Float16* __restrict__ al,
                                                             const _Float16* __restrict__ eh,
                                                             const _Float16* __restrict__ el,
                                                             const float* __restrict__ esq,
                                                             const float* __restrict__ xsq,
                                                             unsigned long long* __restrict__ packed) {
    __shared__ half8 AhT[2][4 * CHUNKS], AlT[2][4 * CHUNKS];
    __shared__ float redv[128][2];
    __shared__ int   redi[128][2];

    const int tid = threadIdx.x;
    const int lane = tid & 63, wave = tid >> 6;
    const int wm = wave >> 1, wn = wave & 1;      // 2x2 wave grid
    const int tx = lane & 15, qd = lane >> 4;
    const int bm = blockIdx.x & 127, bn = blockIdx.x >> 7;   // XCD-aware swizzle
    const int m0 = bm * 128, c0 = bn * 128;

    // A staging: thread t handles rows (t>>2) and (t>>2)+64, k-chunk kq=t&3
    const int srow = tid >> 2, skq = tid & 3;
    const _Float16* gA  = ah + (size_t)(m0 + srow) * DIM + skq * 8;
    const _Float16* gAl = al + (size_t)(m0 + srow) * DIM + skq * 8;
    const int cw0 = skq * CHUNKS + srow, cw1 = cw0 + 64;    // LDS chunk indices

    // E-fragment per-lane base: row = c0 + wn*64 + j*16 + tx, k = kt*32 + qd*8
    const _Float16* gBh = eh + (size_t)(c0 + wn * 64 + tx) * DIM + qd * 8;
    const _Float16* gBl = el + (size_t)(c0 + wn * 64 + tx) * DIM + qd * 8;

    floatx4 acc[4][4];
    #pragma unroll
    for (int i = 0; i < 4; ++i)
        #pragma unroll
        for (int j = 0; j < 4; ++j) acc[i][j] = (floatx4){0.f, 0.f, 0.f, 0.f};

    // prologue: load A tile 0, write buf 0
    half8 rA0 = *(const half8*)(gA);
    half8 rA1 = *(const half8*)(gA  + 64 * DIM);
    half8 rL0 = *(const half8*)(gAl);
    half8 rL1 = *(const half8*)(gAl + 64 * DIM);
    AhT[0][cw0] = rA0; AhT[0][cw1] = rA1;
    AlT[0][cw0] = rL0; AlT[0][cw1] = rL1;

    #pragma unroll 1                               // spill guard: do not unroll K-loop
    for (int kt = 0; kt < DIM / 32; ++kt) {
        const int cur = kt & 1, nxt = cur ^ 1;
        const int kb = (kt + 1) * 32;
        const int ke = kt * 32;

        // B fragments: direct L2 reads, issued before the barrier so the
        // barrier wait covers their latency. fbh first (used by pass 1).
        half8 fbh[4], fbl[4];
        #pragma unroll
        for (int j = 0; j < 4; ++j)
            fbh[j] = *(const half8*)(gBh + (size_t)j * 16 * DIM + ke);
        if (kt < DIM / 32 - 1) {                   // A prefetch in flight during compute
            rA0 = *(const half8*)(gA  + kb);
            rA1 = *(const half8*)(gA  + 64 * DIM + kb);
            rL0 = *(const half8*)(gAl + kb);
            rL1 = *(const half8*)(gAl + 64 * DIM + kb);
        }
        #pragma unroll
        for (int j = 0; j < 4; ++j)
            fbl[j] = *(const half8*)(gBl + (size_t)j * 16 * DIM + ke);
        __syncthreads();                           // buf[cur] writes visible

        half8 fa[4];
        #pragma unroll
        for (int i = 0; i < 4; ++i)
            fa[i] = AhT[cur][qd * CHUNKS + wm * 64 + i * 16 + tx];
        #pragma unroll
        for (int i = 0; i < 4; ++i)
            #pragma unroll
            for (int j = 0; j < 4; ++j)
                acc[i][j] = __builtin_amdgcn_mfma_f32_16x16x32_f16(fa[i], fbh[j], acc[i][j], 0, 0, 0);
        #pragma unroll
        for (int i = 0; i < 4; ++i)
            #pragma unroll
            for (int j = 0; j < 4; ++j)
                acc[i][j] = __builtin_amdgcn_mfma_f32_16x16x32_f16(fa[i], fbl[j], acc[i][j], 0, 0, 0);
        #pragma unroll
        for (int i = 0; i < 4; ++i)                // reuse fa regs for A-lo
            fa[i] = AlT[cur][qd * CHUNKS + wm * 64 + i * 16 + tx];
        #pragma unroll
        for (int i = 0; i < 4; ++i)
            #pragma unroll
            for (int j = 0; j < 4; ++j)
                acc[i][j] = __builtin_amdgcn_mfma_f32_16x16x32_f16(fa[i], fbh[j], acc[i][j], 0, 0, 0);

        if (kt < DIM / 32 - 1) {                   // stage next A tile into other buffer
            AhT[nxt][cw0] = rA0; AhT[nxt][cw1] = rA1;
            AlT[nxt][cw0] = rL0; AlT[nxt][cw1] = rL1;
        }
    }

    // ---- epilogue: scores + argmin (identical arithmetic to passing rounds) ----
    float sqe_v[4];
    #pragma unroll
    for (int j = 0; j < 4; ++j) sqe_v[j] = esq[c0 + wn * 64 + j * 16 + tx];
    #pragma unroll
    for (int i = 0; i < 4; ++i) {
        #pragma unroll
        for (int r = 0; r < 4; ++r) {
            int rl = wm * 64 + i * 16 + qd * 4 + r;        // C/D: row = qd*4+reg
            float sx = xsq[m0 + rl];
            float bvv = FLT_MAX; int bii = 0x7fffffff;
            #pragma unroll
            for (int j = 0; j < 4; ++j) {
                float S = sx + sqe_v[j];                   // fl(sqx + sqe)
                float s = S - acc[i][j][r] * (1.0f / 67108864.0f);  // fl(S - 2m)
                int c = c0 + wn * 64 + j * 16 + tx;
                if (s < bvv || (s == bvv && c < bii)) { bvv = s; bii = c; }
            }
            #pragma unroll
            for (int md = 1; md < 16; md <<= 1) {
                float ov = __shfl_xor(bvv, md, 64);
                int   oc = __shfl_xor(bii, md, 64);
                if (ov < bvv || (ov == bvv && oc < bii)) { bvv = ov; bii = oc; }
            }
            if (tx == 0) { redv[rl][wn] = bvv; redi[rl][wn] = bii; }
        }
    }
    __syncthreads();
    if (tid < 128) {
        float v0 = redv[tid][0], v1 = redv[tid][1];
        int   i0 = redi[tid][0], i1 = redi[tid][1];
        float v = (v1 < v0) ? v1 : v0;            // tie -> wn0 (smaller col)
        int   ix = (v1 < v0) ? i1 : i0;
        // scores positive -> float bits monotonic; lexicographic (bits,idx) min
        // == np.argmin first-occurrence tie-break.
        unsigned long long pk = ((unsigned long long)__float_as_uint(v) << 32)
                              | (unsigned int)ix;
        atomicMin(&packed[m0 + tid], pk);
    }
}

// ---------------- kernel 3: indices + gather quantized + loss from scores ----------------
// loss = 1.25 * mean(min-score): the min score IS fl(||x-e||^2) to ~1e-4/row;
// summed error ~1e-7 << the output threshold. Saves re-reading A (33.5 MB).
// Regrid 256 -> 1024 blocks (16 rows each): old grid was 1 block/CU (3% occ)
// for a 33.5 MB latency-bound gather+write.
__global__ __launch_bounds__(256) void finalize_kernel(const float* __restrict__ E,
                                                       const unsigned long long* __restrict__ packed,
                                                       float* __restrict__ out) {
    float* q = out + 1;
    float* idxF = out + 1 + QELEMS;
    const int tid = threadIdx.x;
    const int r0 = blockIdx.x * 16;

    __shared__ int sidx[16];
    if (tid < 64) {                               // wave 0: unpack idx + score
        float sc = 0.f;
        if (tid < 16) {
            unsigned long long pk = packed[r0 + tid];
            int idx = (int)(unsigned int)(pk & 0xFFFFFFFFull);
            sc = __uint_as_float((unsigned int)(pk >> 32));
            sidx[tid] = idx;
            idxF[r0 + tid] = (float)idx;
        }
        #pragma unroll
        for (int off = 8; off; off >>= 1) sc += __shfl_down(sc, off, 16);
        if (tid == 0) atomicAdd(out, sc * (1.25f / (float)QELEMS));
    }
    __syncthreads();

    #pragma unroll 4
    for (int it = 0; it < 8; ++it) {              // 16 rows * 128 float4 = 2048 slots
        int flat = it * 256 + tid;
        int row = flat >> 7;
        int d4  = (flat & 127) * 4;
        int idx = sidx[row];
        float4 e = *(const float4*)(E + (size_t)idx * DIM + d4);
        *(float4*)(q + (size_t)(r0 + row) * DIM + d4) = e;
    }
}

extern "C" void kernel_launch(void* const* d_in, const int* in_sizes, int n_in,
                              void* d_out, int out_size, void* d_ws, size_t ws_size,
                              hipStream_t stream) {
    const float* A = (const float*)d_in[0];   // inputs (64,256,512)
    const float* E = (const float*)d_in[1];   // emb_weight (1024,512)
    float* out = (float*)d_out;

    unsigned long long* packed = (unsigned long long*)d_ws;     // 16384 u64
    float*    esq  = (float*)(packed + NROWS);                  // 1024
    float*    xsq  = esq + KC;                                  // 16384
    _Float16* eh   = (_Float16*)(xsq + NROWS);                  // 1024*512 (16B-aligned)
    _Float16* el   = eh + (size_t)KC * DIM;
    _Float16* ah   = el + (size_t)KC * DIM;                     // 16384*512
    _Float16* al   = ah + (size_t)NROWS * DIM;

    prep_kernel<<<NROWS / 4 + KC / 4, 256, 0, stream>>>(A, E, xsq, esq, ah, al, eh, el, packed, out);
    mfma_argmin_kernel<<<(NROWS / 128) * NSPLIT, 256, 0, stream>>>(
        ah, al, eh, el, esq, xsq, packed);
    finalize_kernel<<<NROWS / 16, 256, 0, stream>>>(E, packed, out);
}

// Round 2
// 187.257 us; speedup vs baseline: 1.0016x; 1.0016x over previous
//
#include <hip/hip_runtime.h>
#include <cfloat>

// Problem constants: inputs (64,256,512) fp32, emb (1024,512) fp32.
#define NROWS  16384          // 64*256
#define DIM    512
#define KC     1024
#define QELEMS (NROWS * DIM)  // 8388608
// d_out layout (fp32): [0]=loss, [1 .. QELEMS]=quantized, [1+QELEMS .. +NROWS]=indices (as float)

#define NSPLIT 8              // one per 128-code column block
#define CHUNKS 130            // padded kq-plane stride in 16B chunks (128 rows + 2 pad)

typedef float  floatx4 __attribute__((ext_vector_type(4)));
typedef _Float16 half8 __attribute__((ext_vector_type(8)));
typedef _Float16 half4 __attribute__((ext_vector_type(4)));

// ---------------- kernel 1: fused prep (A and E) ----------------
// blocks [0,4096): A rows; [4096,4352): E rows. rowsq tree + split math VERBATIM
// from the passing rounds (part of the verified rounding structure).
__global__ __launch_bounds__(256) void prep_kernel(const float* __restrict__ A,
                                                   const float* __restrict__ E,
                                                   float* __restrict__ xsq,
                                                   float* __restrict__ esq,
                                                   _Float16* __restrict__ ah,
                                                   _Float16* __restrict__ al,
                                                   _Float16* __restrict__ eh,
                                                   _Float16* __restrict__ el,
                                                   unsigned long long* __restrict__ packed,
                                                   float* __restrict__ out) {
    if (blockIdx.x == 0 && threadIdx.x == 0) out[0] = 0.f;
    const int wave = threadIdx.x >> 6, lane = threadIdx.x & 63;
    const bool isA = blockIdx.x < (NROWS / 4);
    const int row = (isA ? blockIdx.x : blockIdx.x - NROWS / 4) * 4 + wave;
    const float* M = isA ? A : E;
    const float scale = isA ? 2048.0f : 65536.0f;

    const float4* Mr = (const float4*)(M + (size_t)row * DIM);
    float4 va = Mr[lane];
    float4 vb = Mr[lane + 64];
    float s = 0.f;
    s += va.x*va.x + va.y*va.y + va.z*va.z + va.w*va.w;   // same tree as rowsq i=0
    s += vb.x*vb.x + vb.y*vb.y + vb.z*vb.z + vb.w*vb.w;   // i=1
    #pragma unroll
    for (int off = 32; off; off >>= 1) s += __shfl_down(s, off, 64);
    if (lane == 0) {
        if (isA) { xsq[row] = s; packed[row] = ~0ULL; }
        else     { esq[row] = s; }
    }

    float xa[4] = {va.x, va.y, va.z, va.w}, xb[4] = {vb.x, vb.y, vb.z, vb.w};
    half4 ha, la, hb, lb;
    #pragma unroll
    for (int e = 0; e < 4; ++e) {
        float t = xa[e] * scale;
        _Float16 h = (_Float16)t;
        ha[e] = h; la[e] = (_Float16)(t - (float)h);
        t = xb[e] * scale;
        h = (_Float16)t;
        hb[e] = h; lb[e] = (_Float16)(t - (float)h);
    }
    _Float16* hr = (isA ? ah : eh) + (size_t)row * DIM;
    _Float16* lr = (isA ? al : el) + (size_t)row * DIM;
    ((half4*)hr)[lane]      = ha;
    ((half4*)lr)[lane]      = la;
    ((half4*)hr)[lane + 64] = hb;
    ((half4*)lr)[lane + 64] = lb;
}

// ---------------- kernel 2: MFMA distance GEMM + fused argmin ----------------
// Round-1 post-mortem: direct-L2 E reads gave the predicted occupancy (28%) and
// conflict (-75%) gains, but the ISSUE ORDER [fbh][A-prefetch][fbl] made the
// pass-2 wait on fbl an effective vmcnt(0): it drained the A HBM prefetch
// (~900cy) mid-compute every kt -> +12us. vmcnt is issue-ordered; a load is
// only "free" if everything issued after it is also allowed to complete.
// Fix (this round):
//   * fbh is PIPELINED one kt ahead (nbh regs): pass 1/3 operands are a full
//     compute phase old -> wait vmcnt(12)-class, no stall.
//   * fbl (current kt) is issued FIRST in the iteration, before A prefetch and
//     nbh: its pass-2 wait is vmcnt(8), A + nbh stay in flight; its L2 latency
//     is covered by barrier + fa ds_reads + pass 1 (16 MFMA).
//   * A prefetch again consumed ONLY at the tail ds_write (vmcnt<=4) -> full
//     HBM latency hiding restored (the round-6 property).
//   * fbl NOT double-buffered: that would peak ~172 live regs (>170 = 512/3
//     budget at 3 waves/SIMD) and risk spill; this scheme peaks ~156.
// Numerics bit-identical: same fb values, same MFMA order per acc element
// (hi*bh, hi*bl, lo*bh), epilogue verbatim.
__global__ __launch_bounds__(256, 3) void mfma_argmin_kernel(const _Float16* __restrict__ ah,
                                                             const _Float16* __restrict__ al,
                                                             const _Float16* __restrict__ eh,
                                                             const _Float16* __restrict__ el,
                                                             const float* __restrict__ esq,
                                                             const float* __restrict__ xsq,
                                                             unsigned long long* __restrict__ packed) {
    __shared__ half8 AhT[2][4 * CHUNKS], AlT[2][4 * CHUNKS];
    __shared__ float redv[128][2];
    __shared__ int   redi[128][2];

    const int tid = threadIdx.x;
    const int lane = tid & 63, wave = tid >> 6;
    const int wm = wave >> 1, wn = wave & 1;      // 2x2 wave grid
    const int tx = lane & 15, qd = lane >> 4;
    const int bm = blockIdx.x & 127, bn = blockIdx.x >> 7;   // XCD-aware swizzle
    const int m0 = bm * 128, c0 = bn * 128;

    // A staging: thread t handles rows (t>>2) and (t>>2)+64, k-chunk kq=t&3
    const int srow = tid >> 2, skq = tid & 3;
    const _Float16* gA  = ah + (size_t)(m0 + srow) * DIM + skq * 8;
    const _Float16* gAl = al + (size_t)(m0 + srow) * DIM + skq * 8;
    const int cw0 = skq * CHUNKS + srow, cw1 = cw0 + 64;    // LDS chunk indices

    // E-fragment per-lane base: row = c0 + wn*64 + j*16 + tx, k = kt*32 + qd*8
    const _Float16* gBh = eh + (size_t)(c0 + wn * 64 + tx) * DIM + qd * 8;
    const _Float16* gBl = el + (size_t)(c0 + wn * 64 + tx) * DIM + qd * 8;

    floatx4 acc[4][4];
    #pragma unroll
    for (int i = 0; i < 4; ++i)
        #pragma unroll
        for (int j = 0; j < 4; ++j) acc[i][j] = (floatx4){0.f, 0.f, 0.f, 0.f};

    // prologue: load A tile 0, write buf 0; load fbh for kt=0
    half8 rA0 = *(const half8*)(gA);
    half8 rA1 = *(const half8*)(gA  + 64 * DIM);
    half8 rL0 = *(const half8*)(gAl);
    half8 rL1 = *(const half8*)(gAl + 64 * DIM);
    AhT[0][cw0] = rA0; AhT[0][cw1] = rA1;
    AlT[0][cw0] = rL0; AlT[0][cw1] = rL1;

    half8 fbh[4], nbh[4];
    #pragma unroll
    for (int j = 0; j < 4; ++j)
        fbh[j] = *(const half8*)(gBh + (size_t)j * 16 * DIM);

    #pragma unroll 1                               // spill guard: do not unroll K-loop
    for (int kt = 0; kt < DIM / 32; ++kt) {
        const int cur = kt & 1, nxt = cur ^ 1;
        const int kb = (kt + 1) * 32;
        const int ke = kt * 32;

        // current-kt B-lo FIRST: everything issued after it may stay in flight
        // when pass 2 waits on it.
        half8 fbl[4];
        #pragma unroll
        for (int j = 0; j < 4; ++j)
            fbl[j] = *(const half8*)(gBl + (size_t)j * 16 * DIM + ke);
        if (kt < DIM / 32 - 1) {                   // in flight during compute
            rA0 = *(const half8*)(gA  + kb);
            rA1 = *(const half8*)(gA  + 64 * DIM + kb);
            rL0 = *(const half8*)(gAl + kb);
            rL1 = *(const half8*)(gAl + 64 * DIM + kb);
            #pragma unroll
            for (int j = 0; j < 4; ++j)            // next-kt B-hi (pipelined)
                nbh[j] = *(const half8*)(gBh + (size_t)j * 16 * DIM + kb);
        }
        __syncthreads();                           // buf[cur] writes visible

        half8 fa[4];
        #pragma unroll
        for (int i = 0; i < 4; ++i)
            fa[i] = AhT[cur][qd * CHUNKS + wm * 64 + i * 16 + tx];
        #pragma unroll
        for (int i = 0; i < 4; ++i)
            #pragma unroll
            for (int j = 0; j < 4; ++j)
                acc[i][j] = __builtin_amdgcn_mfma_f32_16x16x32_f16(fa[i], fbh[j], acc[i][j], 0, 0, 0);
        #pragma unroll
        for (int i = 0; i < 4; ++i)
            #pragma unroll
            for (int j = 0; j < 4; ++j)
                acc[i][j] = __builtin_amdgcn_mfma_f32_16x16x32_f16(fa[i], fbl[j], acc[i][j], 0, 0, 0);
        #pragma unroll
        for (int i = 0; i < 4; ++i)                // reuse fa regs for A-lo
            fa[i] = AlT[cur][qd * CHUNKS + wm * 64 + i * 16 + tx];
        #pragma unroll
        for (int i = 0; i < 4; ++i)
            #pragma unroll
            for (int j = 0; j < 4; ++j)
                acc[i][j] = __builtin_amdgcn_mfma_f32_16x16x32_f16(fa[i], fbh[j], acc[i][j], 0, 0, 0);

        if (kt < DIM / 32 - 1) {                   // tail: consume A prefetch,
            AhT[nxt][cw0] = rA0; AhT[nxt][cw1] = rA1;     // rotate pipelined B-hi
            AlT[nxt][cw0] = rL0; AlT[nxt][cw1] = rL1;
            #pragma unroll
            for (int j = 0; j < 4; ++j) fbh[j] = nbh[j];
        }
    }

    // ---- epilogue: scores + argmin (identical arithmetic to passing rounds) ----
    float sqe_v[4];
    #pragma unroll
    for (int j = 0; j < 4; ++j) sqe_v[j] = esq[c0 + wn * 64 + j * 16 + tx];
    #pragma unroll
    for (int i = 0; i < 4; ++i) {
        #pragma unroll
        for (int r = 0; r < 4; ++r) {
            int rl = wm * 64 + i * 16 + qd * 4 + r;        // C/D: row = qd*4+reg
            float sx = xsq[m0 + rl];
            float bvv = FLT_MAX; int bii = 0x7fffffff;
            #pragma unroll
            for (int j = 0; j < 4; ++j) {
                float S = sx + sqe_v[j];                   // fl(sqx + sqe)
                float s = S - acc[i][j][r] * (1.0f / 67108864.0f);  // fl(S - 2m)
                int c = c0 + wn * 64 + j * 16 + tx;
                if (s < bvv || (s == bvv && c < bii)) { bvv = s; bii = c; }
            }
            #pragma unroll
            for (int md = 1; md < 16; md <<= 1) {
                float ov = __shfl_xor(bvv, md, 64);
                int   oc = __shfl_xor(bii, md, 64);
                if (ov < bvv || (ov == bvv && oc < bii)) { bvv = ov; bii = oc; }
            }
            if (tx == 0) { redv[rl][wn] = bvv; redi[rl][wn] = bii; }
        }
    }
    __syncthreads();
    if (tid < 128) {
        float v0 = redv[tid][0], v1 = redv[tid][1];
        int   i0 = redi[tid][0], i1 = redi[tid][1];
        float v = (v1 < v0) ? v1 : v0;            // tie -> wn0 (smaller col)
        int   ix = (v1 < v0) ? i1 : i0;
        // scores positive -> float bits monotonic; lexicographic (bits,idx) min
        // == np.argmin first-occurrence tie-break.
        unsigned long long pk = ((unsigned long long)__float_as_uint(v) << 32)
                              | (unsigned int)ix;
        atomicMin(&packed[m0 + tid], pk);
    }
}

// ---------------- kernel 3: indices + gather quantized + loss from scores ----------------
// loss = 1.25 * mean(min-score): the min score IS fl(||x-e||^2) to ~1e-4/row;
// summed error ~1e-7 << the output threshold. Saves re-reading A (33.5 MB).
__global__ __launch_bounds__(256) void finalize_kernel(const float* __restrict__ E,
                                                       const unsigned long long* __restrict__ packed,
                                                       float* __restrict__ out) {
    float* q = out + 1;
    float* idxF = out + 1 + QELEMS;
    const int tid = threadIdx.x;
    const int r0 = blockIdx.x * 16;

    __shared__ int sidx[16];
    if (tid < 64) {                               // wave 0: unpack idx + score
        float sc = 0.f;
        if (tid < 16) {
            unsigned long long pk = packed[r0 + tid];
            int idx = (int)(unsigned int)(pk & 0xFFFFFFFFull);
            sc = __uint_as_float((unsigned int)(pk >> 32));
            sidx[tid] = idx;
            idxF[r0 + tid] = (float)idx;
        }
        #pragma unroll
        for (int off = 8; off; off >>= 1) sc += __shfl_down(sc, off, 16);
        if (tid == 0) atomicAdd(out, sc * (1.25f / (float)QELEMS));
    }
    __syncthreads();

    #pragma unroll 4
    for (int it = 0; it < 8; ++it) {              // 16 rows * 128 float4 = 2048 slots
        int flat = it * 256 + tid;
        int row = flat >> 7;
        int d4  = (flat & 127) * 4;
        int idx = sidx[row];
        float4 e = *(const float4*)(E + (size_t)idx * DIM + d4);
        *(float4*)(q + (size_t)(r0 + row) * DIM + d4) = e;
    }
}

extern "C" void kernel_launch(void* const* d_in, const int* in_sizes, int n_in,
                              void* d_out, int out_size, void* d_ws, size_t ws_size,
                              hipStream_t stream) {
    const float* A = (const float*)d_in[0];   // inputs (64,256,512)
    const float* E = (const float*)d_in[1];   // emb_weight (1024,512)
    float* out = (float*)d_out;

    unsigned long long* packed = (unsigned long long*)d_ws;     // 16384 u64
    float*    esq  = (float*)(packed + NROWS);                  // 1024
    float*    xsq  = esq + KC;                                  // 16384
    _Float16* eh   = (_Float16*)(xsq + NROWS);                  // 1024*512 (16B-aligned)
    _Float16* el   = eh + (size_t)KC * DIM;
    _Float16* ah   = el + (size_t)KC * DIM;                     // 16384*512
    _Float16* al   = ah + (size_t)NROWS * DIM;

    prep_kernel<<<NROWS / 4 + KC / 4, 256, 0, stream>>>(A, E, xsq, esq, ah, al, eh, el, packed, out);
    mfma_argmin_kernel<<<(NROWS / 128) * NSPLIT, 256, 0, stream>>>(
        ah, al, eh, el, esq, xsq, packed);
    finalize_kernel<<<NROWS / 16, 256, 0, stream>>>(E, packed, out);
}

// Round 3
// 181.098 us; speedup vs baseline: 1.0357x; 1.0340x over previous
//
#include <hip/hip_runtime.h>
#include <cfloat>

// Problem constants: inputs (64,256,512) fp32, emb (1024,512) fp32.
#define NROWS  16384          // 64*256
#define DIM    512
#define KC     1024
#define QELEMS (NROWS * DIM)  // 8388608
// d_out layout (fp32): [0]=loss, [1 .. QELEMS]=quantized, [1+QELEMS .. +NROWS]=indices (as float)

#define NSPLIT 8              // one per 128-code column block
#define CHUNKS 130            // padded kq-plane stride in 16B chunks (128 rows + 2 pad)
// CHUNKS bank math (the round-1/2 counter-backed fix): staging writes use
// chunk = skq*CHUNKS + row; bank of chunk = (chunk*4) mod 32.
//   CHUNKS=132: 132*4 mod 32 = 16 -> skq 0/2 (and 1/3) planes start on the SAME
//     bank -> 2-way write conflict, +8 cyc per ds_write_b128 (round-0's 8.4M).
//   CHUNKS=130: 130*4 mod 32 = 8  -> all four skq planes offset by 8 banks; a
//     quarter-wave's 16 lanes (4 rows x 4 skq) start on 16 DISTINCT banks ->
//     conflict-free writes. Fragment reads (contiguous 16 chunks per
//     quarter-wave) are conflict-free at either value.

typedef float  floatx4 __attribute__((ext_vector_type(4)));
typedef _Float16 half8 __attribute__((ext_vector_type(8)));
typedef _Float16 half4 __attribute__((ext_vector_type(4)));

// ---------------- kernel 1: fused prep (A and E) ----------------
// blocks [0,4096): A rows; [4096,4352): E rows. rowsq tree + split math VERBATIM
// from the passing rounds (part of the verified rounding structure).
__global__ __launch_bounds__(256) void prep_kernel(const float* __restrict__ A,
                                                   const float* __restrict__ E,
                                                   float* __restrict__ xsq,
                                                   float* __restrict__ esq,
                                                   _Float16* __restrict__ ah,
                                                   _Float16* __restrict__ al,
                                                   _Float16* __restrict__ eh,
                                                   _Float16* __restrict__ el,
                                                   unsigned long long* __restrict__ packed,
                                                   float* __restrict__ out) {
    if (blockIdx.x == 0 && threadIdx.x == 0) out[0] = 0.f;
    const int wave = threadIdx.x >> 6, lane = threadIdx.x & 63;
    const bool isA = blockIdx.x < (NROWS / 4);
    const int row = (isA ? blockIdx.x : blockIdx.x - NROWS / 4) * 4 + wave;
    const float* M = isA ? A : E;
    const float scale = isA ? 2048.0f : 65536.0f;

    const float4* Mr = (const float4*)(M + (size_t)row * DIM);
    float4 va = Mr[lane];
    float4 vb = Mr[lane + 64];
    float s = 0.f;
    s += va.x*va.x + va.y*va.y + va.z*va.z + va.w*va.w;   // same tree as rowsq i=0
    s += vb.x*vb.x + vb.y*vb.y + vb.z*vb.z + vb.w*vb.w;   // i=1
    #pragma unroll
    for (int off = 32; off; off >>= 1) s += __shfl_down(s, off, 64);
    if (lane == 0) {
        if (isA) { xsq[row] = s; packed[row] = ~0ULL; }
        else     { esq[row] = s; }
    }

    float xa[4] = {va.x, va.y, va.z, va.w}, xb[4] = {vb.x, vb.y, vb.z, vb.w};
    half4 ha, la, hb, lb;
    #pragma unroll
    for (int e = 0; e < 4; ++e) {
        float t = xa[e] * scale;
        _Float16 h = (_Float16)t;
        ha[e] = h; la[e] = (_Float16)(t - (float)h);
        t = xb[e] * scale;
        h = (_Float16)t;
        hb[e] = h; lb[e] = (_Float16)(t - (float)h);
    }
    _Float16* hr = (isA ? ah : eh) + (size_t)row * DIM;
    _Float16* lr = (isA ? al : el) + (size_t)row * DIM;
    ((half4*)hr)[lane]      = ha;
    ((half4*)lr)[lane]      = la;
    ((half4*)hr)[lane + 64] = hb;
    ((half4*)lr)[lane + 64] = lb;
}

// ---------------- kernel 2: MFMA distance GEMM + fused argmin ----------------
// ROUND-2 POST-MORTEM / REVERT: direct-L2 E reads (rounds 1-2, 89.8us) regressed
// vs this LDS-staged structure (round 0, 77.6us) and were INSENSITIVE to load
// issue order -> the L2 round-trip per kt sits on the barrier-synced critical
// path and 3 blocks/CU can't hide it. Reverting to the proven structure:
// VGPR-staged loads (compiler hoists global->VGPR across barriers), double LDS
// buffer, SINGLE barrier per kt: load(kt+1)->VGPR issued before compute(kt);
// ds_write to buf[nxt] after compute (in-wave DS ops ordered, different buffer).
// Deltas vs round 0 (each counter-backed or catalog-proven):
//   * CHUNKS 132->130: staging writes conflict-free (see bank math at #define).
//   * s_setprio(1) around MFMA clusters (T5): 2 blocks/CU are not mutually
//     barrier-synced -> scheduler can favor the compute-phase block's waves.
// Score keeps the PASSING rounding structure: s = fl( fl(sqx+sqe) - acc*2^-26 ).
// MFMA order per acc element unchanged (hi*bh, hi*bl, lo*bh) -> bit-identical.
__global__ __launch_bounds__(256) void mfma_argmin_kernel(const _Float16* __restrict__ ah,
                                                          const _Float16* __restrict__ al,
                                                          const _Float16* __restrict__ eh,
                                                          const _Float16* __restrict__ el,
                                                          const float* __restrict__ esq,
                                                          const float* __restrict__ xsq,
                                                          unsigned long long* __restrict__ packed) {
    __shared__ half8 AhT[2][4 * CHUNKS], AlT[2][4 * CHUNKS];
    __shared__ half8 EhT[2][4 * CHUNKS], ElT[2][4 * CHUNKS];
    __shared__ float redv[128][2];
    __shared__ int   redi[128][2];

    const int tid = threadIdx.x;
    const int lane = tid & 63, wave = tid >> 6;
    const int wm = wave >> 1, wn = wave & 1;      // 2x2 wave grid
    const int tx = lane & 15, qd = lane >> 4;
    const int bm = blockIdx.x & 127, bn = blockIdx.x >> 7;   // XCD-aware swizzle
    const int m0 = bm * 128, c0 = bn * 128;

    // staging: thread t handles rows (t>>2) and (t>>2)+64, k-chunk kq=t&3
    const int srow = tid >> 2, skq = tid & 3;
    const _Float16* gA  = ah + (size_t)(m0 + srow) * DIM + skq * 8;
    const _Float16* gAl = al + (size_t)(m0 + srow) * DIM + skq * 8;
    const _Float16* gE  = eh + (size_t)(c0 + srow) * DIM + skq * 8;
    const _Float16* gEl = el + (size_t)(c0 + srow) * DIM + skq * 8;
    const int cw0 = skq * CHUNKS + srow, cw1 = cw0 + 64;    // LDS chunk indices

    floatx4 acc[4][4];
    #pragma unroll
    for (int i = 0; i < 4; ++i)
        #pragma unroll
        for (int j = 0; j < 4; ++j) acc[i][j] = (floatx4){0.f, 0.f, 0.f, 0.f};

    // prologue: load tile 0, write buf 0
    half8 rA0  = *(const half8*)(gA);
    half8 rA1  = *(const half8*)(gA  + 64 * DIM);
    half8 rL0  = *(const half8*)(gAl);
    half8 rL1  = *(const half8*)(gAl + 64 * DIM);
    half8 rE0  = *(const half8*)(gE);
    half8 rE1  = *(const half8*)(gE  + 64 * DIM);
    half8 rF0  = *(const half8*)(gEl);
    half8 rF1  = *(const half8*)(gEl + 64 * DIM);
    AhT[0][cw0] = rA0; AhT[0][cw1] = rA1;
    AlT[0][cw0] = rL0; AlT[0][cw1] = rL1;
    EhT[0][cw0] = rE0; EhT[0][cw1] = rE1;
    ElT[0][cw0] = rF0; ElT[0][cw1] = rF1;

    #pragma unroll 1                               // spill guard: do not unroll K-loop
    for (int kt = 0; kt < DIM / 32; ++kt) {
        const int cur = kt & 1, nxt = cur ^ 1;
        const int kb = (kt + 1) * 32;
        if (kt < DIM / 32 - 1) {                   // loads in flight during compute
            rA0 = *(const half8*)(gA  + kb);
            rA1 = *(const half8*)(gA  + 64 * DIM + kb);
            rL0 = *(const half8*)(gAl + kb);
            rL1 = *(const half8*)(gAl + 64 * DIM + kb);
            rE0 = *(const half8*)(gE  + kb);
            rE1 = *(const half8*)(gE  + 64 * DIM + kb);
            rF0 = *(const half8*)(gEl + kb);
            rF1 = *(const half8*)(gEl + 64 * DIM + kb);
        }
        __syncthreads();                           // buf[cur] writes visible

        half8 fa[4], fbh[4], fbl[4];
        #pragma unroll
        for (int i = 0; i < 4; ++i)
            fa[i] = AhT[cur][qd * CHUNKS + wm * 64 + i * 16 + tx];
        #pragma unroll
        for (int j = 0; j < 4; ++j) {
            fbh[j] = EhT[cur][qd * CHUNKS + wn * 64 + j * 16 + tx];
            fbl[j] = ElT[cur][qd * CHUNKS + wn * 64 + j * 16 + tx];
        }
        __builtin_amdgcn_s_setprio(1);             // T5: favor compute-phase wave
        #pragma unroll
        for (int i = 0; i < 4; ++i)
            #pragma unroll
            for (int j = 0; j < 4; ++j)
                acc[i][j] = __builtin_amdgcn_mfma_f32_16x16x32_f16(fa[i], fbh[j], acc[i][j], 0, 0, 0);
        #pragma unroll
        for (int i = 0; i < 4; ++i)
            #pragma unroll
            for (int j = 0; j < 4; ++j)
                acc[i][j] = __builtin_amdgcn_mfma_f32_16x16x32_f16(fa[i], fbl[j], acc[i][j], 0, 0, 0);
        __builtin_amdgcn_s_setprio(0);
        #pragma unroll
        for (int i = 0; i < 4; ++i)                // reuse fa regs for A-lo
            fa[i] = AlT[cur][qd * CHUNKS + wm * 64 + i * 16 + tx];
        __builtin_amdgcn_s_setprio(1);
        #pragma unroll
        for (int i = 0; i < 4; ++i)
            #pragma unroll
            for (int j = 0; j < 4; ++j)
                acc[i][j] = __builtin_amdgcn_mfma_f32_16x16x32_f16(fa[i], fbh[j], acc[i][j], 0, 0, 0);
        __builtin_amdgcn_s_setprio(0);

        if (kt < DIM / 32 - 1) {                   // stage next tile into other buffer
            AhT[nxt][cw0] = rA0; AhT[nxt][cw1] = rA1;
            AlT[nxt][cw0] = rL0; AlT[nxt][cw1] = rL1;
            EhT[nxt][cw0] = rE0; EhT[nxt][cw1] = rE1;
            ElT[nxt][cw0] = rF0; ElT[nxt][cw1] = rF1;
        }
    }

    // ---- epilogue: scores + argmin (identical arithmetic to passing rounds) ----
    float sqe_v[4];
    #pragma unroll
    for (int j = 0; j < 4; ++j) sqe_v[j] = esq[c0 + wn * 64 + j * 16 + tx];
    #pragma unroll
    for (int i = 0; i < 4; ++i) {
        #pragma unroll
        for (int r = 0; r < 4; ++r) {
            int rl = wm * 64 + i * 16 + qd * 4 + r;        // C/D: row = qd*4+reg
            float sx = xsq[m0 + rl];
            float bvv = FLT_MAX; int bii = 0x7fffffff;
            #pragma unroll
            for (int j = 0; j < 4; ++j) {
                float S = sx + sqe_v[j];                   // fl(sqx + sqe)
                float s = S - acc[i][j][r] * (1.0f / 67108864.0f);  // fl(S - 2m)
                int c = c0 + wn * 64 + j * 16 + tx;
                if (s < bvv || (s == bvv && c < bii)) { bvv = s; bii = c; }
            }
            #pragma unroll
            for (int md = 1; md < 16; md <<= 1) {
                float ov = __shfl_xor(bvv, md, 64);
                int   oc = __shfl_xor(bii, md, 64);
                if (ov < bvv || (ov == bvv && oc < bii)) { bvv = ov; bii = oc; }
            }
            if (tx == 0) { redv[rl][wn] = bvv; redi[rl][wn] = bii; }
        }
    }
    __syncthreads();
    if (tid < 128) {
        float v0 = redv[tid][0], v1 = redv[tid][1];
        int   i0 = redi[tid][0], i1 = redi[tid][1];
        float v = (v1 < v0) ? v1 : v0;            // tie -> wn0 (smaller col)
        int   ix = (v1 < v0) ? i1 : i0;
        // scores positive -> float bits monotonic; lexicographic (bits,idx) min
        // == np.argmin first-occurrence tie-break.
        unsigned long long pk = ((unsigned long long)__float_as_uint(v) << 32)
                              | (unsigned int)ix;
        atomicMin(&packed[m0 + tid], pk);
    }
}

// ---------------- kernel 3: indices + gather quantized + loss from scores ----------------
// loss = 1.25 * mean(min-score): the min score IS fl(||x-e||^2) to ~1e-4/row;
// summed error ~1e-7 << the output threshold. Saves re-reading A (33.5 MB).
// 1024 blocks x 16 rows (passed rounds 1-2): old 256-block grid was 1 block/CU
// for a 33.5 MB latency-bound gather+write.
__global__ __launch_bounds__(256) void finalize_kernel(const float* __restrict__ E,
                                                       const unsigned long long* __restrict__ packed,
                                                       float* __restrict__ out) {
    float* q = out + 1;
    float* idxF = out + 1 + QELEMS;
    const int tid = threadIdx.x;
    const int r0 = blockIdx.x * 16;

    __shared__ int sidx[16];
    if (tid < 64) {                               // wave 0: unpack idx + score
        float sc = 0.f;
        if (tid < 16) {
            unsigned long long pk = packed[r0 + tid];
            int idx = (int)(unsigned int)(pk & 0xFFFFFFFFull);
            sc = __uint_as_float((unsigned int)(pk >> 32));
            sidx[tid] = idx;
            idxF[r0 + tid] = (float)idx;
        }
        #pragma unroll
        for (int off = 8; off; off >>= 1) sc += __shfl_down(sc, off, 16);
        if (tid == 0) atomicAdd(out, sc * (1.25f / (float)QELEMS));
    }
    __syncthreads();

    #pragma unroll 4
    for (int it = 0; it < 8; ++it) {              // 16 rows * 128 float4 = 2048 slots
        int flat = it * 256 + tid;
        int row = flat >> 7;
        int d4  = (flat & 127) * 4;
        int idx = sidx[row];
        float4 e = *(const float4*)(E + (size_t)idx * DIM + d4);
        *(float4*)(q + (size_t)(r0 + row) * DIM + d4) = e;
    }
}

extern "C" void kernel_launch(void* const* d_in, const int* in_sizes, int n_in,
                              void* d_out, int out_size, void* d_ws, size_t ws_size,
                              hipStream_t stream) {
    const float* A = (const float*)d_in[0];   // inputs (64,256,512)
    const float* E = (const float*)d_in[1];   // emb_weight (1024,512)
    float* out = (float*)d_out;

    unsigned long long* packed = (unsigned long long*)d_ws;     // 16384 u64
    float*    esq  = (float*)(packed + NROWS);                  // 1024
    float*    xsq  = esq + KC;                                  // 16384
    _Float16* eh   = (_Float16*)(xsq + NROWS);                  // 1024*512 (16B-aligned)
    _Float16* el   = eh + (size_t)KC * DIM;
    _Float16* ah   = el + (size_t)KC * DIM;                     // 16384*512
    _Float16* al   = ah + (size_t)NROWS * DIM;

    prep_kernel<<<NROWS / 4 + KC / 4, 256, 0, stream>>>(A, E, xsq, esq, ah, al, eh, el, packed, out);
    mfma_argmin_kernel<<<(NROWS / 128) * NSPLIT, 256, 0, stream>>>(
        ah, al, eh, el, esq, xsq, packed);
    finalize_kernel<<<NROWS / 16, 256, 0, stream>>>(E, packed, out);
}

// Round 4
// 179.247 us; speedup vs baseline: 1.0464x; 1.0103x over previous
//
#include <hip/hip_runtime.h>
#include <cfloat>

// Problem constants: inputs (64,256,512) fp32, emb (1024,512) fp32.
#define NROWS  16384          // 64*256
#define DIM    512
#define KC     1024
#define QELEMS (NROWS * DIM)  // 8388608
// d_out layout (fp32): [0]=loss, [1 .. QELEMS]=quantized, [1+QELEMS .. +NROWS]=indices (as float)

#define NSPLIT 8              // one per 128-code column block
#define CHUNKS 130            // padded kq-plane stride in 16B chunks (128 rows + 2 pad)
// CHUNKS bank math (round-3 counter-backed: conflicts 8.4M -> 4.2M): staging
// writes use chunk = skq*CHUNKS + row; 130*4 mod 32 = 8 -> the four skq planes
// start 8 banks apart; a quarter-wave's 16 lanes hit 16 distinct banks ->
// conflict-free writes. (132 gave stride 16 -> 2-way write conflicts.)
// Residual 4.2M = 4 cyc per ds_read_b128 = the instruction's inherent
// throughput (m134: ~12 cyc), not a fixable conflict.

typedef float  floatx4 __attribute__((ext_vector_type(4)));
typedef _Float16 half8 __attribute__((ext_vector_type(8)));
typedef _Float16 half4 __attribute__((ext_vector_type(4)));

// ---------------- kernel 1: fused prep (A and E) ----------------
// blocks [0,4096): A rows; [4096,4352): E rows. rowsq tree + split math VERBATIM
// from the passing rounds (part of the verified rounding structure).
__global__ __launch_bounds__(256) void prep_kernel(const float* __restrict__ A,
                                                   const float* __restrict__ E,
                                                   float* __restrict__ xsq,
                                                   float* __restrict__ esq,
                                                   _Float16* __restrict__ ah,
                                                   _Float16* __restrict__ al,
                                                   _Float16* __restrict__ eh,
                                                   _Float16* __restrict__ el,
                                                   unsigned long long* __restrict__ packed,
                                                   float* __restrict__ out) {
    if (blockIdx.x == 0 && threadIdx.x == 0) out[0] = 0.f;
    const int wave = threadIdx.x >> 6, lane = threadIdx.x & 63;
    const bool isA = blockIdx.x < (NROWS / 4);
    const int row = (isA ? blockIdx.x : blockIdx.x - NROWS / 4) * 4 + wave;
    const float* M = isA ? A : E;
    const float scale = isA ? 2048.0f : 65536.0f;

    const float4* Mr = (const float4*)(M + (size_t)row * DIM);
    float4 va = Mr[lane];
    float4 vb = Mr[lane + 64];
    float s = 0.f;
    s += va.x*va.x + va.y*va.y + va.z*va.z + va.w*va.w;   // same tree as rowsq i=0
    s += vb.x*vb.x + vb.y*vb.y + vb.z*vb.z + vb.w*vb.w;   // i=1
    #pragma unroll
    for (int off = 32; off; off >>= 1) s += __shfl_down(s, off, 64);
    if (lane == 0) {
        if (isA) { xsq[row] = s; packed[row] = ~0ULL; }
        else     { esq[row] = s; }
    }

    float xa[4] = {va.x, va.y, va.z, va.w}, xb[4] = {vb.x, vb.y, vb.z, vb.w};
    half4 ha, la, hb, lb;
    #pragma unroll
    for (int e = 0; e < 4; ++e) {
        float t = xa[e] * scale;
        _Float16 h = (_Float16)t;
        ha[e] = h; la[e] = (_Float16)(t - (float)h);
        t = xb[e] * scale;
        h = (_Float16)t;
        hb[e] = h; lb[e] = (_Float16)(t - (float)h);
    }
    _Float16* hr = (isA ? ah : eh) + (size_t)row * DIM;
    _Float16* lr = (isA ? al : el) + (size_t)row * DIM;
    ((half4*)hr)[lane]      = ha;
    ((half4*)lr)[lane]      = la;
    ((half4*)hr)[lane + 64] = hb;
    ((half4*)lr)[lane + 64] = lb;
}

// ---------------- kernel 2: MFMA distance GEMM + fused argmin ----------------
// ROUND-3 POST-MORTEM: conflict fix (8.4M->4.2M) + setprio changed NOTHING ->
// LDS conflicts were off the critical path. Resource math says no pipe >35%
// busy -> latency-bound inside the barrier-bounded kt region. The exposed
// latency: A/E prefetch for kt+1 is issued at top of kt and consumed by the
// SAME iteration's tail ds_write -- only ~500 cyc of compute between issue and
// the vmcnt wait, vs ~900 cyc HBM latency for the cold A stream -> every kt
// ends with a ~300-500 cyc stall that all 4 waves hit together at the barrier.
// FIX (this round): prefetch distance 2. Two NAMED register sets P/Q (rule
// #20: runtime-indexed sets go to scratch), loop hand-unrolled x2. Tile kt+2
// loads issue at top of kt; tail ds_write consumes the set loaded a FULL
// iteration ago (~2900 cyc in flight >> 900) -> tail vmcnt is a no-op.
// Barrier count (16), buffer parity (tile kt -> buf[kt&1]), MFMA order,
// fragment reads, epilogue: byte-identical -> bit-identical numerics.
// LDS caps occupancy at 2 blocks/CU (= 2 waves/SIMD, 256-VGPR budget), so the
// +32 staging VGPRs are free; __launch_bounds__(256,2) guards the allocator.
// Score keeps the PASSING rounding structure: s = fl( fl(sqx+sqe) - acc*2^-26 ).

#define LOAD_SET(S, koff) \
    S##A0 = *(const half8*)(gA  + (koff)); \
    S##A1 = *(const half8*)(gA  + 64 * DIM + (koff)); \
    S##L0 = *(const half8*)(gAl + (koff)); \
    S##L1 = *(const half8*)(gAl + 64 * DIM + (koff)); \
    S##E0 = *(const half8*)(gE  + (koff)); \
    S##E1 = *(const half8*)(gE  + 64 * DIM + (koff)); \
    S##F0 = *(const half8*)(gEl + (koff)); \
    S##F1 = *(const half8*)(gEl + 64 * DIM + (koff));

#define STORE_SET(S, b) \
    AhT[b][cw0] = S##A0; AhT[b][cw1] = S##A1; \
    AlT[b][cw0] = S##L0; AlT[b][cw1] = S##L1; \
    EhT[b][cw0] = S##E0; EhT[b][cw1] = S##E1; \
    ElT[b][cw0] = S##F0; ElT[b][cw1] = S##F1;

#define COMPUTE(b) { \
    half8 fa[4], fbh[4], fbl[4]; \
    _Pragma("unroll") \
    for (int i = 0; i < 4; ++i) \
        fa[i] = AhT[b][qd * CHUNKS + wm * 64 + i * 16 + tx]; \
    _Pragma("unroll") \
    for (int j = 0; j < 4; ++j) { \
        fbh[j] = EhT[b][qd * CHUNKS + wn * 64 + j * 16 + tx]; \
        fbl[j] = ElT[b][qd * CHUNKS + wn * 64 + j * 16 + tx]; \
    } \
    __builtin_amdgcn_s_setprio(1); \
    _Pragma("unroll") \
    for (int i = 0; i < 4; ++i) \
        _Pragma("unroll") \
        for (int j = 0; j < 4; ++j) \
            acc[i][j] = __builtin_amdgcn_mfma_f32_16x16x32_f16(fa[i], fbh[j], acc[i][j], 0, 0, 0); \
    _Pragma("unroll") \
    for (int i = 0; i < 4; ++i) \
        _Pragma("unroll") \
        for (int j = 0; j < 4; ++j) \
            acc[i][j] = __builtin_amdgcn_mfma_f32_16x16x32_f16(fa[i], fbl[j], acc[i][j], 0, 0, 0); \
    __builtin_amdgcn_s_setprio(0); \
    _Pragma("unroll") \
    for (int i = 0; i < 4; ++i) \
        fa[i] = AlT[b][qd * CHUNKS + wm * 64 + i * 16 + tx]; \
    __builtin_amdgcn_s_setprio(1); \
    _Pragma("unroll") \
    for (int i = 0; i < 4; ++i) \
        _Pragma("unroll") \
        for (int j = 0; j < 4; ++j) \
            acc[i][j] = __builtin_amdgcn_mfma_f32_16x16x32_f16(fa[i], fbh[j], acc[i][j], 0, 0, 0); \
    __builtin_amdgcn_s_setprio(0); \
}

__global__ __launch_bounds__(256, 2) void mfma_argmin_kernel(const _Float16* __restrict__ ah,
                                                             const _Float16* __restrict__ al,
                                                             const _Float16* __restrict__ eh,
                                                             const _Float16* __restrict__ el,
                                                             const float* __restrict__ esq,
                                                             const float* __restrict__ xsq,
                                                             unsigned long long* __restrict__ packed) {
    __shared__ half8 AhT[2][4 * CHUNKS], AlT[2][4 * CHUNKS];
    __shared__ half8 EhT[2][4 * CHUNKS], ElT[2][4 * CHUNKS];
    __shared__ float redv[128][2];
    __shared__ int   redi[128][2];

    const int tid = threadIdx.x;
    const int lane = tid & 63, wave = tid >> 6;
    const int wm = wave >> 1, wn = wave & 1;      // 2x2 wave grid
    const int tx = lane & 15, qd = lane >> 4;
    const int bm = blockIdx.x & 127, bn = blockIdx.x >> 7;   // XCD-aware swizzle
    const int m0 = bm * 128, c0 = bn * 128;

    // staging: thread t handles rows (t>>2) and (t>>2)+64, k-chunk kq=t&3
    const int srow = tid >> 2, skq = tid & 3;
    const _Float16* gA  = ah + (size_t)(m0 + srow) * DIM + skq * 8;
    const _Float16* gAl = al + (size_t)(m0 + srow) * DIM + skq * 8;
    const _Float16* gE  = eh + (size_t)(c0 + srow) * DIM + skq * 8;
    const _Float16* gEl = el + (size_t)(c0 + srow) * DIM + skq * 8;
    const int cw0 = skq * CHUNKS + srow, cw1 = cw0 + 64;    // LDS chunk indices

    floatx4 acc[4][4];
    #pragma unroll
    for (int i = 0; i < 4; ++i)
        #pragma unroll
        for (int j = 0; j < 4; ++j) acc[i][j] = (floatx4){0.f, 0.f, 0.f, 0.f};

    // two named staging sets (prefetch distance 2)
    half8 pA0, pA1, pL0, pL1, pE0, pE1, pF0, pF1;
    half8 qA0, qA1, qL0, qL1, qE0, qE1, qF0, qF1;

    // prologue: tile0 -> LDS buf0 (vmcnt(0) once); tile1 -> Q, stays in flight
    LOAD_SET(p, 0);
    STORE_SET(p, 0);
    LOAD_SET(q, 32);

    #pragma unroll 1                               // spill guard: 8 macro-iters
    for (int k2 = 0; k2 < 8; ++k2) {
        const int kt = k2 * 2;
        // ---- even step: compute tile kt from buf0 ----
        if (kt + 2 < 16) { LOAD_SET(p, (kt + 2) * 32); }    // tile kt+2 -> P
        __syncthreads();                           // buf0 writes visible
        COMPUTE(0);
        STORE_SET(q, 1);                           // tile kt+1 (loaded 1 iter ago) -> buf1
        // ---- odd step: compute tile kt+1 from buf1 ----
        if (kt + 3 < 16) { LOAD_SET(q, (kt + 3) * 32); }    // tile kt+3 -> Q
        __syncthreads();                           // buf1 writes visible
        COMPUTE(1);
        if (kt + 2 < 16) { STORE_SET(p, 0); }      // tile kt+2 -> buf0
    }

    // ---- epilogue: scores + argmin (identical arithmetic to passing rounds) ----
    float sqe_v[4];
    #pragma unroll
    for (int j = 0; j < 4; ++j) sqe_v[j] = esq[c0 + wn * 64 + j * 16 + tx];
    #pragma unroll
    for (int i = 0; i < 4; ++i) {
        #pragma unroll
        for (int r = 0; r < 4; ++r) {
            int rl = wm * 64 + i * 16 + qd * 4 + r;        // C/D: row = qd*4+reg
            float sx = xsq[m0 + rl];
            float bvv = FLT_MAX; int bii = 0x7fffffff;
            #pragma unroll
            for (int j = 0; j < 4; ++j) {
                float S = sx + sqe_v[j];                   // fl(sqx + sqe)
                float s = S - acc[i][j][r] * (1.0f / 67108864.0f);  // fl(S - 2m)
                int c = c0 + wn * 64 + j * 16 + tx;
                if (s < bvv || (s == bvv && c < bii)) { bvv = s; bii = c; }
            }
            #pragma unroll
            for (int md = 1; md < 16; md <<= 1) {
                float ov = __shfl_xor(bvv, md, 64);
                int   oc = __shfl_xor(bii, md, 64);
                if (ov < bvv || (ov == bvv && oc < bii)) { bvv = ov; bii = oc; }
            }
            if (tx == 0) { redv[rl][wn] = bvv; redi[rl][wn] = bii; }
        }
    }
    __syncthreads();
    if (tid < 128) {
        float v0 = redv[tid][0], v1 = redv[tid][1];
        int   i0 = redi[tid][0], i1 = redi[tid][1];
        float v = (v1 < v0) ? v1 : v0;            // tie -> wn0 (smaller col)
        int   ix = (v1 < v0) ? i1 : i0;
        // scores positive -> float bits monotonic; lexicographic (bits,idx) min
        // == np.argmin first-occurrence tie-break.
        unsigned long long pk = ((unsigned long long)__float_as_uint(v) << 32)
                              | (unsigned int)ix;
        atomicMin(&packed[m0 + tid], pk);
    }
}

// ---------------- kernel 3: indices + gather quantized + loss from scores ----------------
// loss = 1.25 * mean(min-score): the min score IS fl(||x-e||^2) to ~1e-4/row;
// summed error ~1e-7 << the output threshold. Saves re-reading A (33.5 MB).
// 1024 blocks x 16 rows (passed rounds 1-3): 256-block grid was 1 block/CU.
__global__ __launch_bounds__(256) void finalize_kernel(const float* __restrict__ E,
                                                       const unsigned long long* __restrict__ packed,
                                                       float* __restrict__ out) {
    float* q = out + 1;
    float* idxF = out + 1 + QELEMS;
    const int tid = threadIdx.x;
    const int r0 = blockIdx.x * 16;

    __shared__ int sidx[16];
    if (tid < 64) {                               // wave 0: unpack idx + score
        float sc = 0.f;
        if (tid < 16) {
            unsigned long long pk = packed[r0 + tid];
            int idx = (int)(unsigned int)(pk & 0xFFFFFFFFull);
            sc = __uint_as_float((unsigned int)(pk >> 32));
            sidx[tid] = idx;
            idxF[r0 + tid] = (float)idx;
        }
        #pragma unroll
        for (int off = 8; off; off >>= 1) sc += __shfl_down(sc, off, 16);
        if (tid == 0) atomicAdd(out, sc * (1.25f / (float)QELEMS));
    }
    __syncthreads();

    #pragma unroll 4
    for (int it = 0; it < 8; ++it) {              // 16 rows * 128 float4 = 2048 slots
        int flat = it * 256 + tid;
        int row = flat >> 7;
        int d4  = (flat & 127) * 4;
        int idx = sidx[row];
        float4 e = *(const float4*)(E + (size_t)idx * DIM + d4);
        *(float4*)(q + (size_t)(r0 + row) * DIM + d4) = e;
    }
}

extern "C" void kernel_launch(void* const* d_in, const int* in_sizes, int n_in,
                              void* d_out, int out_size, void* d_ws, size_t ws_size,
                              hipStream_t stream) {
    const float* A = (const float*)d_in[0];   // inputs (64,256,512)
    const float* E = (const float*)d_in[1];   // emb_weight (1024,512)
    float* out = (float*)d_out;

    unsigned long long* packed = (unsigned long long*)d_ws;     // 16384 u64
    float*    esq  = (float*)(packed + NROWS);                  // 1024
    float*    xsq  = esq + KC;                                  // 16384
    _Float16* eh   = (_Float16*)(xsq + NROWS);                  // 1024*512 (16B-aligned)
    _Float16* el   = eh + (size_t)KC * DIM;
    _Float16* ah   = el + (size_t)KC * DIM;                     // 16384*512
    _Float16* al   = ah + (size_t)NROWS * DIM;

    prep_kernel<<<NROWS / 4 + KC / 4, 256, 0, stream>>>(A, E, xsq, esq, ah, al, eh, el, packed, out);
    mfma_argmin_kernel<<<(NROWS / 128) * NSPLIT, 256, 0, stream>>>(
        ah, al, eh, el, esq, xsq, packed);
    finalize_kernel<<<NROWS / 16, 256, 0, stream>>>(E, packed, out);
}

// Round 5
// 176.865 us; speedup vs baseline: 1.0605x; 1.0135x over previous
//
#include <hip/hip_runtime.h>
#include <cfloat>

// Problem constants: inputs (64,256,512) fp32, emb (1024,512) fp32.
#define NROWS  16384          // 64*256
#define DIM    512
#define KC     1024
#define QELEMS (NROWS * DIM)  // 8388608
// d_out layout (fp32): [0]=loss, [1 .. QELEMS]=quantized, [1+QELEMS .. +NROWS]=indices (as float)

#define NSPLIT 8              // one per 128-code column block
#define CHUNKS 130            // padded kq-plane stride in 16B chunks (128 rows + 2 pad)
// CHUNKS bank math (round-3 counter-backed: conflicts 8.4M -> 4.2M): staging
// writes use chunk = skq*CHUNKS + row; 130*4 mod 32 = 8 -> the four skq planes
// start 8 banks apart; quarter-wave's 16 lanes hit 16 distinct banks ->
// conflict-free writes. Residual 4.2M = ds_read_b128 inherent throughput.

typedef float  floatx4 __attribute__((ext_vector_type(4)));
typedef _Float16 half8 __attribute__((ext_vector_type(8)));
typedef _Float16 half4 __attribute__((ext_vector_type(4)));

// ROUND-4 POST-MORTEM: conflict-fix, setprio, and prefetch-distance-2 ALL landed
// at exactly 77.0us -> they share a structural bottleneck. It is the barrier:
// hipcc emits `s_waitcnt vmcnt(0) lgkmcnt(0)` before every s_barrier
// (__syncthreads drains ALL memory ops — learn_hip m97 asm evidence). So every
// kt the ENTIRE prefetch queue drains at the barrier: "loads in flight during
// compute" never existed, and HBM latency (~900cy cold A stream) serializes
// into each of the 16 kt for both resident blocks. This also retro-explains
// rounds 1-2 (insensitive to issue order: everything drained anyway).
// FIX: the 8-phase template's verified plain-HIP barrier (T4, m194-m201):
//   asm volatile("s_waitcnt lgkmcnt(0)" ::: "memory");  // own LDS ops done
//   __builtin_amdgcn_s_barrier();                        // rendezvous
// -> vmem prefetches stay in flight across the barrier; the compiler inserts
// COUNTED vmcnt(N) only at the ds_writes that consume the prefetched regs
// (register dependency), e.g. vmcnt(8) leaving the newer set outstanding.
// With the P/Q distance-2 pipeline this becomes a real 2-deep pipeline.
// Memory clobber pins LDS ops on the correct side; buffer-reuse hazard is
// covered because each STORE_SET follows a barrier whose lgkmcnt(0) drained
// every wave's reads of that buffer. No value/order change -> bit-identical.
#define KBARRIER() do { \
    asm volatile("s_waitcnt lgkmcnt(0)" ::: "memory"); \
    __builtin_amdgcn_s_barrier(); \
} while (0)

// ---------------- kernel 1: fused prep (A and E) ----------------
// blocks [0,4096): A rows; [4096,4352): E rows. rowsq tree + split math VERBATIM
// from the passing rounds (part of the verified rounding structure).
__global__ __launch_bounds__(256) void prep_kernel(const float* __restrict__ A,
                                                   const float* __restrict__ E,
                                                   float* __restrict__ xsq,
                                                   float* __restrict__ esq,
                                                   _Float16* __restrict__ ah,
                                                   _Float16* __restrict__ al,
                                                   _Float16* __restrict__ eh,
                                                   _Float16* __restrict__ el,
                                                   unsigned long long* __restrict__ packed,
                                                   float* __restrict__ out) {
    if (blockIdx.x == 0 && threadIdx.x == 0) out[0] = 0.f;
    const int wave = threadIdx.x >> 6, lane = threadIdx.x & 63;
    const bool isA = blockIdx.x < (NROWS / 4);
    const int row = (isA ? blockIdx.x : blockIdx.x - NROWS / 4) * 4 + wave;
    const float* M = isA ? A : E;
    const float scale = isA ? 2048.0f : 65536.0f;

    const float4* Mr = (const float4*)(M + (size_t)row * DIM);
    float4 va = Mr[lane];
    float4 vb = Mr[lane + 64];
    float s = 0.f;
    s += va.x*va.x + va.y*va.y + va.z*va.z + va.w*va.w;   // same tree as rowsq i=0
    s += vb.x*vb.x + vb.y*vb.y + vb.z*vb.z + vb.w*vb.w;   // i=1
    #pragma unroll
    for (int off = 32; off; off >>= 1) s += __shfl_down(s, off, 64);
    if (lane == 0) {
        if (isA) { xsq[row] = s; packed[row] = ~0ULL; }
        else     { esq[row] = s; }
    }

    float xa[4] = {va.x, va.y, va.z, va.w}, xb[4] = {vb.x, vb.y, vb.z, vb.w};
    half4 ha, la, hb, lb;
    #pragma unroll
    for (int e = 0; e < 4; ++e) {
        float t = xa[e] * scale;
        _Float16 h = (_Float16)t;
        ha[e] = h; la[e] = (_Float16)(t - (float)h);
        t = xb[e] * scale;
        h = (_Float16)t;
        hb[e] = h; lb[e] = (_Float16)(t - (float)h);
    }
    _Float16* hr = (isA ? ah : eh) + (size_t)row * DIM;
    _Float16* lr = (isA ? al : el) + (size_t)row * DIM;
    ((half4*)hr)[lane]      = ha;
    ((half4*)lr)[lane]      = la;
    ((half4*)hr)[lane + 64] = hb;
    ((half4*)lr)[lane + 64] = lb;
}

// ---------------- kernel 2: MFMA distance GEMM + fused argmin ----------------
#define LOAD_SET(S, koff) \
    S##A0 = *(const half8*)(gA  + (koff)); \
    S##A1 = *(const half8*)(gA  + 64 * DIM + (koff)); \
    S##L0 = *(const half8*)(gAl + (koff)); \
    S##L1 = *(const half8*)(gAl + 64 * DIM + (koff)); \
    S##E0 = *(const half8*)(gE  + (koff)); \
    S##E1 = *(const half8*)(gE  + 64 * DIM + (koff)); \
    S##F0 = *(const half8*)(gEl + (koff)); \
    S##F1 = *(const half8*)(gEl + 64 * DIM + (koff));

#define STORE_SET(S, b) \
    AhT[b][cw0] = S##A0; AhT[b][cw1] = S##A1; \
    AlT[b][cw0] = S##L0; AlT[b][cw1] = S##L1; \
    EhT[b][cw0] = S##E0; EhT[b][cw1] = S##E1; \
    ElT[b][cw0] = S##F0; ElT[b][cw1] = S##F1;

#define COMPUTE(b) { \
    half8 fa[4], fbh[4], fbl[4]; \
    _Pragma("unroll") \
    for (int i = 0; i < 4; ++i) \
        fa[i] = AhT[b][qd * CHUNKS + wm * 64 + i * 16 + tx]; \
    _Pragma("unroll") \
    for (int j = 0; j < 4; ++j) { \
        fbh[j] = EhT[b][qd * CHUNKS + wn * 64 + j * 16 + tx]; \
        fbl[j] = ElT[b][qd * CHUNKS + wn * 64 + j * 16 + tx]; \
    } \
    __builtin_amdgcn_s_setprio(1); \
    _Pragma("unroll") \
    for (int i = 0; i < 4; ++i) \
        _Pragma("unroll") \
        for (int j = 0; j < 4; ++j) \
            acc[i][j] = __builtin_amdgcn_mfma_f32_16x16x32_f16(fa[i], fbh[j], acc[i][j], 0, 0, 0); \
    _Pragma("unroll") \
    for (int i = 0; i < 4; ++i) \
        _Pragma("unroll") \
        for (int j = 0; j < 4; ++j) \
            acc[i][j] = __builtin_amdgcn_mfma_f32_16x16x32_f16(fa[i], fbl[j], acc[i][j], 0, 0, 0); \
    __builtin_amdgcn_s_setprio(0); \
    _Pragma("unroll") \
    for (int i = 0; i < 4; ++i) \
        fa[i] = AlT[b][qd * CHUNKS + wm * 64 + i * 16 + tx]; \
    __builtin_amdgcn_s_setprio(1); \
    _Pragma("unroll") \
    for (int i = 0; i < 4; ++i) \
        _Pragma("unroll") \
        for (int j = 0; j < 4; ++j) \
            acc[i][j] = __builtin_amdgcn_mfma_f32_16x16x32_f16(fa[i], fbh[j], acc[i][j], 0, 0, 0); \
    __builtin_amdgcn_s_setprio(0); \
}

__global__ __launch_bounds__(256, 2) void mfma_argmin_kernel(const _Float16* __restrict__ ah,
                                                             const _Float16* __restrict__ al,
                                                             const _Float16* __restrict__ eh,
                                                             const _Float16* __restrict__ el,
                                                             const float* __restrict__ esq,
                                                             const float* __restrict__ xsq,
                                                             unsigned long long* __restrict__ packed) {
    __shared__ half8 AhT[2][4 * CHUNKS], AlT[2][4 * CHUNKS];
    __shared__ half8 EhT[2][4 * CHUNKS], ElT[2][4 * CHUNKS];
    __shared__ float redv[128][2];
    __shared__ int   redi[128][2];

    const int tid = threadIdx.x;
    const int lane = tid & 63, wave = tid >> 6;
    const int wm = wave >> 1, wn = wave & 1;      // 2x2 wave grid
    const int tx = lane & 15, qd = lane >> 4;
    const int bm = blockIdx.x & 127, bn = blockIdx.x >> 7;   // XCD-aware swizzle
    const int m0 = bm * 128, c0 = bn * 128;

    // staging: thread t handles rows (t>>2) and (t>>2)+64, k-chunk kq=t&3
    const int srow = tid >> 2, skq = tid & 3;
    const _Float16* gA  = ah + (size_t)(m0 + srow) * DIM + skq * 8;
    const _Float16* gAl = al + (size_t)(m0 + srow) * DIM + skq * 8;
    const _Float16* gE  = eh + (size_t)(c0 + srow) * DIM + skq * 8;
    const _Float16* gEl = el + (size_t)(c0 + srow) * DIM + skq * 8;
    const int cw0 = skq * CHUNKS + srow, cw1 = cw0 + 64;    // LDS chunk indices

    floatx4 acc[4][4];
    #pragma unroll
    for (int i = 0; i < 4; ++i)
        #pragma unroll
        for (int j = 0; j < 4; ++j) acc[i][j] = (floatx4){0.f, 0.f, 0.f, 0.f};

    // two named staging sets (prefetch distance 2; rule #20: named, not indexed)
    half8 pA0, pA1, pL0, pL1, pE0, pE1, pF0, pF1;
    half8 qA0, qA1, qL0, qL1, qE0, qE1, qF0, qF1;

    // prologue: tile0 -> LDS buf0; tile1 -> Q, stays in flight across barriers
    LOAD_SET(p, 0);
    STORE_SET(p, 0);
    LOAD_SET(q, 32);

    #pragma unroll 1                               // spill guard: 8 macro-iters
    for (int k2 = 0; k2 < 8; ++k2) {
        const int kt = k2 * 2;
        // ---- even step: compute tile kt from buf0 ----
        if (kt + 2 < 16) { LOAD_SET(p, (kt + 2) * 32); }    // tile kt+2 -> P
        KBARRIER();                                // buf0 visible; vmem NOT drained
        COMPUTE(0);
        STORE_SET(q, 1);                           // waits vmcnt(8): only Q's loads
        // ---- odd step: compute tile kt+1 from buf1 ----
        if (kt + 3 < 16) { LOAD_SET(q, (kt + 3) * 32); }    // tile kt+3 -> Q
        KBARRIER();                                // buf1 visible; vmem NOT drained
        COMPUTE(1);
        if (kt + 2 < 16) { STORE_SET(p, 0); }      // waits vmcnt(8): only P's loads
    }

    // ---- epilogue: scores + argmin (identical arithmetic to passing rounds) ----
    float sqe_v[4];
    #pragma unroll
    for (int j = 0; j < 4; ++j) sqe_v[j] = esq[c0 + wn * 64 + j * 16 + tx];
    #pragma unroll
    for (int i = 0; i < 4; ++i) {
        #pragma unroll
        for (int r = 0; r < 4; ++r) {
            int rl = wm * 64 + i * 16 + qd * 4 + r;        // C/D: row = qd*4+reg
            float sx = xsq[m0 + rl];
            float bvv = FLT_MAX; int bii = 0x7fffffff;
            #pragma unroll
            for (int j = 0; j < 4; ++j) {
                float S = sx + sqe_v[j];                   // fl(sqx + sqe)
                float s = S - acc[i][j][r] * (1.0f / 67108864.0f);  // fl(S - 2m)
                int c = c0 + wn * 64 + j * 16 + tx;
                if (s < bvv || (s == bvv && c < bii)) { bvv = s; bii = c; }
            }
            #pragma unroll
            for (int md = 1; md < 16; md <<= 1) {
                float ov = __shfl_xor(bvv, md, 64);
                int   oc = __shfl_xor(bii, md, 64);
                if (ov < bvv || (ov == bvv && oc < bii)) { bvv = ov; bii = oc; }
            }
            if (tx == 0) { redv[rl][wn] = bvv; redi[rl][wn] = bii; }
        }
    }
    __syncthreads();
    if (tid < 128) {
        float v0 = redv[tid][0], v1 = redv[tid][1];
        int   i0 = redi[tid][0], i1 = redi[tid][1];
        float v = (v1 < v0) ? v1 : v0;            // tie -> wn0 (smaller col)
        int   ix = (v1 < v0) ? i1 : i0;
        // scores positive -> float bits monotonic; lexicographic (bits,idx) min
        // == np.argmin first-occurrence tie-break.
        unsigned long long pk = ((unsigned long long)__float_as_uint(v) << 32)
                              | (unsigned int)ix;
        atomicMin(&packed[m0 + tid], pk);
    }
}

// ---------------- kernel 3: indices + gather quantized + loss from scores ----------------
// loss = 1.25 * mean(min-score): the min score IS fl(||x-e||^2) to ~1e-4/row;
// summed error ~1e-7 << the output threshold. Saves re-reading A (33.5 MB).
// 1024 blocks x 16 rows (passed rounds 1-4): 256-block grid was 1 block/CU.
__global__ __launch_bounds__(256) void finalize_kernel(const float* __restrict__ E,
                                                       const unsigned long long* __restrict__ packed,
                                                       float* __restrict__ out) {
    float* q = out + 1;
    float* idxF = out + 1 + QELEMS;
    const int tid = threadIdx.x;
    const int r0 = blockIdx.x * 16;

    __shared__ int sidx[16];
    if (tid < 64) {                               // wave 0: unpack idx + score
        float sc = 0.f;
        if (tid < 16) {
            unsigned long long pk = packed[r0 + tid];
            int idx = (int)(unsigned int)(pk & 0xFFFFFFFFull);
            sc = __uint_as_float((unsigned int)(pk >> 32));
            sidx[tid] = idx;
            idxF[r0 + tid] = (float)idx;
        }
        #pragma unroll
        for (int off = 8; off; off >>= 1) sc += __shfl_down(sc, off, 16);
        if (tid == 0) atomicAdd(out, sc * (1.25f / (float)QELEMS));
    }
    __syncthreads();

    #pragma unroll 4
    for (int it = 0; it < 8; ++it) {              // 16 rows * 128 float4 = 2048 slots
        int flat = it * 256 + tid;
        int row = flat >> 7;
        int d4  = (flat & 127) * 4;
        int idx = sidx[row];
        float4 e = *(const float4*)(E + (size_t)idx * DIM + d4);
        *(float4*)(q + (size_t)(r0 + row) * DIM + d4) = e;
    }
}

extern "C" void kernel_launch(void* const* d_in, const int* in_sizes, int n_in,
                              void* d_out, int out_size, void* d_ws, size_t ws_size,
                              hipStream_t stream) {
    const float* A = (const float*)d_in[0];   // inputs (64,256,512)
    const float* E = (const float*)d_in[1];   // emb_weight (1024,512)
    float* out = (float*)d_out;

    unsigned long long* packed = (unsigned long long*)d_ws;     // 16384 u64
    float*    esq  = (float*)(packed + NROWS);                  // 1024
    float*    xsq  = esq + KC;                                  // 16384
    _Float16* eh   = (_Float16*)(xsq + NROWS);                  // 1024*512 (16B-aligned)
    _Float16* el   = eh + (size_t)KC * DIM;
    _Float16* ah   = el + (size_t)KC * DIM;                     // 16384*512
    _Float16* al   = ah + (size_t)NROWS * DIM;

    prep_kernel<<<NROWS / 4 + KC / 4, 256, 0, stream>>>(A, E, xsq, esq, ah, al, eh, el, packed, out);
    mfma_argmin_kernel<<<(NROWS / 128) * NSPLIT, 256, 0, stream>>>(
        ah, al, eh, el, esq, xsq, packed);
    finalize_kernel<<<NROWS / 16, 256, 0, stream>>>(E, packed, out);
}

// Round 6
// 174.269 us; speedup vs baseline: 1.0763x; 1.0149x over previous
//
#include <hip/hip_runtime.h>
#include <cfloat>

// Problem constants: inputs (64,256,512) fp32, emb (1024,512) fp32.
#define NROWS  16384          // 64*256
#define DIM    512
#define KC     1024
#define QELEMS (NROWS * DIM)  // 8388608
// d_out layout (fp32): [0]=loss, [1 .. QELEMS]=quantized, [1+QELEMS .. +NROWS]=indices (as float)

#define NSPLIT 8              // one per 128-code column block
#define CHUNKS 130            // padded kq-plane stride in 16B chunks (128 rows + 2 pad)
// CHUNKS bank math (round-3 counter-backed: conflicts 8.4M -> 4.2M): staging
// writes use chunk = skq*CHUNKS + row; 130*4 mod 32 = 8 -> the four skq planes
// start 8 banks apart; quarter-wave's 16 lanes hit 16 distinct banks ->
// conflict-free writes. Residual 4.2M = ds_read_b128 inherent throughput.

typedef float  floatx4 __attribute__((ext_vector_type(4)));
typedef _Float16 half8 __attribute__((ext_vector_type(8)));
typedef _Float16 half4 __attribute__((ext_vector_type(4)));

// ROUND-5 POST-MORTEM: FOUR schedules (issue order, prefetch depth 1/2, full
// __syncthreads drain, lgkm-only KBARRIER) all land at 77.0+-0.5us -> none of
// those was the binding constraint. Resource recount with per-SIMD MFMA cost
// (19.4 cyc/SIMD for 16x16x32): per measured kt-period (~5775 cyc) each pipe
// does ~1900 cyc of work - MFMA ~30%, LDS ~33%, VALU ~17%, HBM 7.5%. Nothing
// saturated: the kernel is PHASE-SERIALIZED at 2 blocks/CU (2 waves/SIMD).
// Within a kt, read->MFMA->write->barrier serialize and there is no foreign
// wave to fill the gaps. The unexplored lever is OCCUPANCY with fragments
// still LDS-local (rounds 1-2 raised occupancy but moved fragments onto the
// L2 critical path - that regression was the fragment source, not occupancy).
// THIS ROUND: single-buffer the LDS tile (34.5KB, was 68.6KB double-buffered)
// + 2 KBARRIERs per kt. LDS now allows 4 blocks/CU; VGPR (~160 live) allows 3
// at __launch_bounds__(256,3) -> 3 blocks/CU, 12 waves, +50% TLP. Staging regs
// are consumed by ds_write one FULL kt after their load issues (~2000cy in
// flight >> 900cy HBM) and KBARRIER (lgkm-only) keeps them in flight across
// barriers. Store-data WAR is safe: stores capture reg data at in-order issue.
// Numerics: identical values, identical MFMA order -> bit-identical.
#define KBARRIER() do { \
    asm volatile("s_waitcnt lgkmcnt(0)" ::: "memory"); \
    __builtin_amdgcn_s_barrier(); \
} while (0)

// ---------------- kernel 1: fused prep (A and E) ----------------
// blocks [0,4096): A rows; [4096,4352): E rows. rowsq tree + split math VERBATIM
// from the passing rounds (part of the verified rounding structure).
__global__ __launch_bounds__(256) void prep_kernel(const float* __restrict__ A,
                                                   const float* __restrict__ E,
                                                   float* __restrict__ xsq,
                                                   float* __restrict__ esq,
                                                   _Float16* __restrict__ ah,
                                                   _Float16* __restrict__ al,
                                                   _Float16* __restrict__ eh,
                                                   _Float16* __restrict__ el,
                                                   unsigned long long* __restrict__ packed,
                                                   float* __restrict__ out) {
    if (blockIdx.x == 0 && threadIdx.x == 0) out[0] = 0.f;
    const int wave = threadIdx.x >> 6, lane = threadIdx.x & 63;
    const bool isA = blockIdx.x < (NROWS / 4);
    const int row = (isA ? blockIdx.x : blockIdx.x - NROWS / 4) * 4 + wave;
    const float* M = isA ? A : E;
    const float scale = isA ? 2048.0f : 65536.0f;

    const float4* Mr = (const float4*)(M + (size_t)row * DIM);
    float4 va = Mr[lane];
    float4 vb = Mr[lane + 64];
    float s = 0.f;
    s += va.x*va.x + va.y*va.y + va.z*va.z + va.w*va.w;   // same tree as rowsq i=0
    s += vb.x*vb.x + vb.y*vb.y + vb.z*vb.z + vb.w*vb.w;   // i=1
    #pragma unroll
    for (int off = 32; off; off >>= 1) s += __shfl_down(s, off, 64);
    if (lane == 0) {
        if (isA) { xsq[row] = s; packed[row] = ~0ULL; }
        else     { esq[row] = s; }
    }

    float xa[4] = {va.x, va.y, va.z, va.w}, xb[4] = {vb.x, vb.y, vb.z, vb.w};
    half4 ha, la, hb, lb;
    #pragma unroll
    for (int e = 0; e < 4; ++e) {
        float t = xa[e] * scale;
        _Float16 h = (_Float16)t;
        ha[e] = h; la[e] = (_Float16)(t - (float)h);
        t = xb[e] * scale;
        h = (_Float16)t;
        hb[e] = h; lb[e] = (_Float16)(t - (float)h);
    }
    _Float16* hr = (isA ? ah : eh) + (size_t)row * DIM;
    _Float16* lr = (isA ? al : el) + (size_t)row * DIM;
    ((half4*)hr)[lane]      = ha;
    ((half4*)lr)[lane]      = la;
    ((half4*)hr)[lane + 64] = hb;
    ((half4*)lr)[lane + 64] = lb;
}

// ---------------- kernel 2: MFMA distance GEMM + fused argmin ----------------
#define LOAD_SET(S, koff) \
    S##A0 = *(const half8*)(gA  + (koff)); \
    S##A1 = *(const half8*)(gA  + 64 * DIM + (koff)); \
    S##L0 = *(const half8*)(gAl + (koff)); \
    S##L1 = *(const half8*)(gAl + 64 * DIM + (koff)); \
    S##E0 = *(const half8*)(gE  + (koff)); \
    S##E1 = *(const half8*)(gE  + 64 * DIM + (koff)); \
    S##F0 = *(const half8*)(gEl + (koff)); \
    S##F1 = *(const half8*)(gEl + 64 * DIM + (koff));

#define STORE_SET(S) \
    AhT[cw0] = S##A0; AhT[cw1] = S##A1; \
    AlT[cw0] = S##L0; AlT[cw1] = S##L1; \
    EhT[cw0] = S##E0; EhT[cw1] = S##E1; \
    ElT[cw0] = S##F0; ElT[cw1] = S##F1;

#define COMPUTE() { \
    half8 fa[4], fbh[4], fbl[4]; \
    _Pragma("unroll") \
    for (int i = 0; i < 4; ++i) \
        fa[i] = AhT[qd * CHUNKS + wm * 64 + i * 16 + tx]; \
    _Pragma("unroll") \
    for (int j = 0; j < 4; ++j) { \
        fbh[j] = EhT[qd * CHUNKS + wn * 64 + j * 16 + tx]; \
        fbl[j] = ElT[qd * CHUNKS + wn * 64 + j * 16 + tx]; \
    } \
    __builtin_amdgcn_s_setprio(1); \
    _Pragma("unroll") \
    for (int i = 0; i < 4; ++i) \
        _Pragma("unroll") \
        for (int j = 0; j < 4; ++j) \
            acc[i][j] = __builtin_amdgcn_mfma_f32_16x16x32_f16(fa[i], fbh[j], acc[i][j], 0, 0, 0); \
    _Pragma("unroll") \
    for (int i = 0; i < 4; ++i) \
        _Pragma("unroll") \
        for (int j = 0; j < 4; ++j) \
            acc[i][j] = __builtin_amdgcn_mfma_f32_16x16x32_f16(fa[i], fbl[j], acc[i][j], 0, 0, 0); \
    __builtin_amdgcn_s_setprio(0); \
    _Pragma("unroll") \
    for (int i = 0; i < 4; ++i) \
        fa[i] = AlT[qd * CHUNKS + wm * 64 + i * 16 + tx]; \
    __builtin_amdgcn_s_setprio(1); \
    _Pragma("unroll") \
    for (int i = 0; i < 4; ++i) \
        _Pragma("unroll") \
        for (int j = 0; j < 4; ++j) \
            acc[i][j] = __builtin_amdgcn_mfma_f32_16x16x32_f16(fa[i], fbh[j], acc[i][j], 0, 0, 0); \
    __builtin_amdgcn_s_setprio(0); \
}

__global__ __launch_bounds__(256, 3) void mfma_argmin_kernel(const _Float16* __restrict__ ah,
                                                             const _Float16* __restrict__ al,
                                                             const _Float16* __restrict__ eh,
                                                             const _Float16* __restrict__ el,
                                                             const float* __restrict__ esq,
                                                             const float* __restrict__ xsq,
                                                             unsigned long long* __restrict__ packed) {
    __shared__ half8 AhT[4 * CHUNKS], AlT[4 * CHUNKS];     // SINGLE buffer: 34.5KB
    __shared__ half8 EhT[4 * CHUNKS], ElT[4 * CHUNKS];     // -> 3 blocks/CU (VGPR-capped)
    __shared__ float redv[128][2];
    __shared__ int   redi[128][2];

    const int tid = threadIdx.x;
    const int lane = tid & 63, wave = tid >> 6;
    const int wm = wave >> 1, wn = wave & 1;      // 2x2 wave grid
    const int tx = lane & 15, qd = lane >> 4;
    const int bm = blockIdx.x & 127, bn = blockIdx.x >> 7;   // XCD-aware swizzle
    const int m0 = bm * 128, c0 = bn * 128;

    // staging: thread t handles rows (t>>2) and (t>>2)+64, k-chunk kq=t&3
    const int srow = tid >> 2, skq = tid & 3;
    const _Float16* gA  = ah + (size_t)(m0 + srow) * DIM + skq * 8;
    const _Float16* gAl = al + (size_t)(m0 + srow) * DIM + skq * 8;
    const _Float16* gE  = eh + (size_t)(c0 + srow) * DIM + skq * 8;
    const _Float16* gEl = el + (size_t)(c0 + srow) * DIM + skq * 8;
    const int cw0 = skq * CHUNKS + srow, cw1 = cw0 + 64;    // LDS chunk indices

    floatx4 acc[4][4];
    #pragma unroll
    for (int i = 0; i < 4; ++i)
        #pragma unroll
        for (int j = 0; j < 4; ++j) acc[i][j] = (floatx4){0.f, 0.f, 0.f, 0.f};

    // one named staging set (rule #20: named regs, not runtime-indexed)
    half8 sA0, sA1, sL0, sL1, sE0, sE1, sF0, sF1;

    // prologue: tile0 -> LDS (one vmcnt(0) at the stores); tile1 -> regs,
    // stays in flight across the first barrier + compute.
    LOAD_SET(s, 0);
    STORE_SET(s);
    LOAD_SET(s, 32);

    #pragma unroll 1                               // spill guard
    for (int kt = 0; kt < 16; ++kt) {
        KBARRIER();                                // tile kt writes visible (lgkm only)
        COMPUTE();                                 // tile kt from LDS
        if (kt < 15) {
            KBARRIER();                            // all waves done READING tile kt
            STORE_SET(s);                          // tile kt+1 regs -> LDS (counted
                                                   // vmcnt: waits only these 8 loads)
            if (kt < 14) { LOAD_SET(s, (kt + 2) * 32); }  // refill: in flight a full kt
        }
    }

    // ---- epilogue: scores + argmin (identical arithmetic to passing rounds) ----
    float sqe_v[4];
    #pragma unroll
    for (int j = 0; j < 4; ++j) sqe_v[j] = esq[c0 + wn * 64 + j * 16 + tx];
    #pragma unroll
    for (int i = 0; i < 4; ++i) {
        #pragma unroll
        for (int r = 0; r < 4; ++r) {
            int rl = wm * 64 + i * 16 + qd * 4 + r;        // C/D: row = qd*4+reg
            float sx = xsq[m0 + rl];
            float bvv = FLT_MAX; int bii = 0x7fffffff;
            #pragma unroll
            for (int j = 0; j < 4; ++j) {
                float S = sx + sqe_v[j];                   // fl(sqx + sqe)
                float s = S - acc[i][j][r] * (1.0f / 67108864.0f);  // fl(S - 2m)
                int c = c0 + wn * 64 + j * 16 + tx;
                if (s < bvv || (s == bvv && c < bii)) { bvv = s; bii = c; }
            }
            #pragma unroll
            for (int md = 1; md < 16; md <<= 1) {
                float ov = __shfl_xor(bvv, md, 64);
                int   oc = __shfl_xor(bii, md, 64);
                if (ov < bvv || (ov == bvv && oc < bii)) { bvv = ov; bii = oc; }
            }
            if (tx == 0) { redv[rl][wn] = bvv; redi[rl][wn] = bii; }
        }
    }
    __syncthreads();
    if (tid < 128) {
        float v0 = redv[tid][0], v1 = redv[tid][1];
        int   i0 = redi[tid][0], i1 = redi[tid][1];
        float v = (v1 < v0) ? v1 : v0;            // tie -> wn0 (smaller col)
        int   ix = (v1 < v0) ? i1 : i0;
        // scores positive -> float bits monotonic; lexicographic (bits,idx) min
        // == np.argmin first-occurrence tie-break.
        unsigned long long pk = ((unsigned long long)__float_as_uint(v) << 32)
                              | (unsigned int)ix;
        atomicMin(&packed[m0 + tid], pk);
    }
}

// ---------------- kernel 3: indices + gather quantized + loss from scores ----------------
// loss = 1.25 * mean(min-score): the min score IS fl(||x-e||^2) to ~1e-4/row;
// summed error ~1e-7 << the output threshold. Saves re-reading A (33.5 MB).
// 1024 blocks x 16 rows (passed rounds 1-5): 256-block grid was 1 block/CU.
__global__ __launch_bounds__(256) void finalize_kernel(const float* __restrict__ E,
                                                       const unsigned long long* __restrict__ packed,
                                                       float* __restrict__ out) {
    float* q = out + 1;
    float* idxF = out + 1 + QELEMS;
    const int tid = threadIdx.x;
    const int r0 = blockIdx.x * 16;

    __shared__ int sidx[16];
    if (tid < 64) {                               // wave 0: unpack idx + score
        float sc = 0.f;
        if (tid < 16) {
            unsigned long long pk = packed[r0 + tid];
            int idx = (int)(unsigned int)(pk & 0xFFFFFFFFull);
            sc = __uint_as_float((unsigned int)(pk >> 32));
            sidx[tid] = idx;
            idxF[r0 + tid] = (float)idx;
        }
        #pragma unroll
        for (int off = 8; off; off >>= 1) sc += __shfl_down(sc, off, 16);
        if (tid == 0) atomicAdd(out, sc * (1.25f / (float)QELEMS));
    }
    __syncthreads();

    #pragma unroll 4
    for (int it = 0; it < 8; ++it) {              // 16 rows * 128 float4 = 2048 slots
        int flat = it * 256 + tid;
        int row = flat >> 7;
        int d4  = (flat & 127) * 4;
        int idx = sidx[row];
        float4 e = *(const float4*)(E + (size_t)idx * DIM + d4);
        *(float4*)(q + (size_t)(r0 + row) * DIM + d4) = e;
    }
}

extern "C" void kernel_launch(void* const* d_in, const int* in_sizes, int n_in,
                              void* d_out, int out_size, void* d_ws, size_t ws_size,
                              hipStream_t stream) {
    const float* A = (const float*)d_in[0];   // inputs (64,256,512)
    const float* E = (const float*)d_in[1];   // emb_weight (1024,512)
    float* out = (float*)d_out;

    unsigned long long* packed = (unsigned long long*)d_ws;     // 16384 u64
    float*    esq  = (float*)(packed + NROWS);                  // 1024
    float*    xsq  = esq + KC;                                  // 16384
    _Float16* eh   = (_Float16*)(xsq + NROWS);                  // 1024*512 (16B-aligned)
    _Float16* el   = eh + (size_t)KC * DIM;
    _Float16* ah   = el + (size_t)KC * DIM;                     // 16384*512
    _Float16* al   = ah + (size_t)NROWS * DIM;

    prep_kernel<<<NROWS / 4 + KC / 4, 256, 0, stream>>>(A, E, xsq, esq, ah, al, eh, el, packed, out);
    mfma_argmin_kernel<<<(NROWS / 128) * NSPLIT, 256, 0, stream>>>(
        ah, al, eh, el, esq, xsq, packed);
    finalize_kernel<<<NROWS / 16, 256, 0, stream>>>(E, packed, out);
}